// Round 10
// baseline (252.507 us; speedup 1.0000x reference)
//
#include <hip/hip_runtime.h>
#include <hip/hip_bf16.h>

using u16 = unsigned short;
using u32 = unsigned int;

typedef short bf16x8 __attribute__((ext_vector_type(8)));
typedef float f32x4 __attribute__((ext_vector_type(4)));

#define AS1 __attribute__((address_space(1)))
#define AS3 __attribute__((address_space(3)))

__device__ __forceinline__ void gll16(const void* g, void* l) {
  __builtin_amdgcn_global_load_lds((const AS1 u32*)g, (AS3 u32*)l, 16, 0, 0);
}

__device__ __forceinline__ u16 f2bf(float x) {  // round-to-nearest-even bf16
  u32 u = __builtin_bit_cast(u32, x);
  u32 r = (u + 0x7fffu + ((u >> 16) & 1u)) >> 16;
  return (u16)r;
}
__device__ __forceinline__ u32 pk2(float lo, float hi) {
  return (u32)f2bf(lo) | ((u32)f2bf(hi) << 16);
}
__device__ __forceinline__ u16 f2bf_fast(float x) {  // hw cvt (validated r5/r6)
  __hip_bfloat16 h = __float2bfloat16(x);
  return __builtin_bit_cast(u16, h);
}

// ---------------- merged prep: x cast (blocks 0..4095) + 4 weight transposes ----------------
__device__ __forceinline__ void trans64(const float* __restrict__ in, u16* __restrict__ out,
                                        int R, int Cc, int bx, int by, float (*tl)[65]) {
  int c0 = bx * 64, r0 = by * 64, tid = threadIdx.x;
#pragma unroll
  for (int i = 0; i < 16; i++) {
    int idx = i * 256 + tid; int tr = idx >> 6, tc = idx & 63;
    tl[tr][tc] = in[(size_t)(r0 + tr) * Cc + c0 + tc];
  }
  __syncthreads();
#pragma unroll
  for (int i = 0; i < 16; i++) {
    int idx = i * 256 + tid; int tr = idx >> 6, tc = idx & 63;
    out[(size_t)(c0 + tr) * R + r0 + tc] = f2bf(tl[tc][tr]);
  }
}

__global__ void k_prep(const float* __restrict__ x, u16* __restrict__ xb,
                       const float* __restrict__ wq, u16* __restrict__ wqt,
                       const float* __restrict__ wk, const float* __restrict__ wv,
                       u16* __restrict__ wkvt,
                       const float* __restrict__ wo, u16* __restrict__ wot) {
  __shared__ float tl[64][65];
  int gid = blockIdx.x;
  if (gid < 4096) {
    int i = gid * 256 + threadIdx.x;
    const float4* p = (const float4*)(x + (size_t)i * 8);
    float4 a = p[0], b = p[1];
    uint4 o;
    o.x = pk2(a.x, a.y); o.y = pk2(a.z, a.w);
    o.z = pk2(b.x, b.y); o.w = pk2(b.z, b.w);
    *(uint4*)(xb + (size_t)i * 8) = o;
  } else if (gid < 5120) {
    int t = gid - 4096; trans64(wq, wqt, 2048, 2048, t & 31, t >> 5, tl);
  } else if (gid < 5376) {
    int t = gid - 5120; trans64(wk, wkvt, 2048, 512, t & 7, t >> 3, tl);
  } else if (gid < 5632) {
    int t = gid - 5376; trans64(wv, wkvt + 512 * 2048, 2048, 512, t & 7, t >> 3, tl);
  } else {
    int t = gid - 5632; trans64(wo, wot, 2048, 2048, t & 31, t >> 5, tl);
  }
}

// ---------------- GEMM: C = A[M][K] x BT[N][K], 128x128 tile, BK=64, 4 waves ----------------
// MODE 0: C f32 [4096][2048] (O projection). grid (16,32).
// MODE 3: fused QKV. grid (24,32): bx<16 -> Q: rms+rope*(log2e/sqrt(D)) -> bf16 Cout;
//         bx 16..19 -> K: rms+rope -> Kout; bx 20..23 -> V: bf16^T -> Vout (b,kvh,d,t).
// Both grids XCD-swizzled (nwg % 8 == 0, bijective).
template <int MODE>
__global__ __launch_bounds__(256) void k_gemm(
    const u16* __restrict__ A, const u16* __restrict__ BT0, const u16* __restrict__ BT1,
    void* __restrict__ Cout, u16* __restrict__ Kout, u16* __restrict__ Vout, int K,
    const float* __restrict__ nwq, const float* __restrict__ nwk,
    const float* __restrict__ fc, const float* __restrict__ fs) {
  constexpr int NX = (MODE == 0) ? 16 : 24;
  constexpr int NWG = NX * 32;
  __shared__ char lds[32768];
  char* As = lds; char* Bs = lds + 16384;
  int tid = threadIdx.x, w = tid >> 6, l = tid & 63, lg = l >> 4, ll = l & 15;
  // XCD-aware bijective remap
  int lid = blockIdx.y * NX + blockIdx.x;
  int nid = (lid & 7) * (NWG >> 3) + (lid >> 3);
  int bxt = nid % NX;
  int bm0 = (nid / NX) * 128;
  bool qpath = (MODE == 0) || (bxt < 16);
  const u16* BT = qpath ? BT0 : BT1;
  int bn0 = qpath ? bxt * 128 : (bxt - 16) * 128;
  int wr = w >> 1, wc = w & 1;
  f32x4 acc[4][4] = {};
  for (int k0 = 0; k0 < K; k0 += 64) {
#pragma unroll
    for (int i = 0; i < 4; i++) {
      int base = i * 256 + (w << 6);       // wave-uniform chunk base
      int p = base + l;                    // this lane's 16B chunk
      int r = p >> 3, kc = (p & 7) ^ (r & 7);  // pre-swizzled global source
      gll16(A + (size_t)(bm0 + r) * K + k0 + kc * 8, As + base * 16);
      gll16(BT + (size_t)(bn0 + r) * K + k0 + kc * 8, Bs + base * 16);
    }
    asm volatile("s_waitcnt vmcnt(0)" ::: "memory");
    __syncthreads();
#pragma unroll
    for (int ks = 0; ks < 2; ks++) {
      bf16x8 af[4], bfr[4];
#pragma unroll
      for (int m = 0; m < 4; m++) {
        int row = 64 * wr + 16 * m + ll;
        af[m] = *(const bf16x8*)(As + row * 128 + (((lg + 4 * ks) ^ (row & 7)) << 4));
      }
#pragma unroll
      for (int n = 0; n < 4; n++) {
        int row = 64 * wc + 16 * n + ll;
        bfr[n] = *(const bf16x8*)(Bs + row * 128 + (((lg + 4 * ks) ^ (row & 7)) << 4));
      }
#pragma unroll
      for (int m = 0; m < 4; m++)
#pragma unroll
        for (int n = 0; n < 4; n++)
          acc[m][n] = __builtin_amdgcn_mfma_f32_16x16x32_bf16(af[m], bfr[n], acc[m][n], 0, 0, 0);
    }
    __syncthreads();
  }

  if (MODE == 0) {
    float* C = (float*)Cout;
#pragma unroll
    for (int m = 0; m < 4; m++)
#pragma unroll
      for (int n = 0; n < 4; n++) {
        int row = bm0 + 64 * wr + 16 * m + 4 * lg;
        int col = bn0 + 64 * wc + 16 * n + ll;
        float* cp = C + (size_t)row * 2048 + col;
#pragma unroll
        for (int r = 0; r < 4; r++) cp[(size_t)r * 2048] = acc[m][n][r];
      }
    return;
  }

  if (qpath || bn0 < 512) {
    // --- fused RMSNorm + RoPE + bf16 store (Q or K heads) ---
    const float* nw = qpath ? nwq : nwk;
    u16* O = qpath ? (u16*)Cout : Kout;
    int ostride = qpath ? 2048 : 512;
    // Q: log2e/sqrt(128) (exp2-domain attention); K: 1
    float outscale = qpath ? 0.12751744843f : 1.0f;
    float* ssum = (float*)lds;  // [wr][64 rows][wc]
    float ps[4][4];
#pragma unroll
    for (int m = 0; m < 4; m++)
#pragma unroll
      for (int r = 0; r < 4; r++) {
        float p = 0.f;
#pragma unroll
        for (int n = 0; n < 4; n++) p += acc[m][n][r] * acc[m][n][r];
#pragma unroll
        for (int msk = 1; msk < 16; msk <<= 1) p += __shfl_xor(p, msk);
        ps[m][r] = p;
      }
    if (ll == 0) {
#pragma unroll
      for (int m = 0; m < 4; m++)
#pragma unroll
        for (int r = 0; r < 4; r++)
          ssum[wr * 128 + (16 * m + 4 * lg + r) * 2 + wc] = ps[m][r];
    }
    __syncthreads();
    float rs[4][4];
#pragma unroll
    for (int m = 0; m < 4; m++)
#pragma unroll
      for (int r = 0; r < 4; r++) {
        int rowl = 16 * m + 4 * lg + r;
        float tot = ssum[wr * 128 + rowl * 2] + ssum[wr * 128 + rowl * 2 + 1];
        rs[m][r] = rsqrtf(tot * (1.0f / 128.0f) + 1e-5f) * outscale;
      }
#pragma unroll
    for (int m = 0; m < 4; m++)
#pragma unroll
      for (int n = 0; n < 4; n++) {
        int d = 64 * wc + 16 * n + ll;     // dim within head (0..127)
        float wgt = nw[d];
        int i = d >> 1;
#pragma unroll
        for (int r = 0; r < 4; r++) {
          int row = bm0 + 64 * wr + 16 * m + 4 * lg + r;
          int t = row & 2047;
          float y = acc[m][n][r] * rs[m][r] * wgt;
          float p = __shfl_xor(y, 1);       // partner of the RoPE pair
          if (!(ll & 1)) {                   // even lane: y=xr, p=xi; stores both
            float c = fc[t * 64 + i], s = fs[t * 64 + i];
            u32 pk = pk2(y * c - p * s, y * s + p * c);
            *(u32*)(O + (size_t)row * ostride + bn0 + d) = pk;
          }
        }
      }
  } else {
    // --- V: bf16 + transpose to (b,kvh,d,t) via swizzled LDS ---
    int b = bm0 >> 11, t0g = bm0 & 2047;
    int kvh = (bn0 - 512) >> 7;
    int bk = b * 4 + kvh;
#pragma unroll
    for (int m = 0; m < 4; m++)
#pragma unroll
      for (int n = 0; n < 4; n++) {
        int d = 64 * wc + 16 * n + ll;
        int tloc = 64 * wr + 16 * m + 4 * lg;
        u32 w0 = pk2(acc[m][n][0], acc[m][n][1]);
        u32 w1 = pk2(acc[m][n][2], acc[m][n][3]);
        int byte = (d * 256 + tloc * 2) ^ ((d & 7) << 4);
        *(uint2*)(lds + byte) = make_uint2(w0, w1);
      }
    __syncthreads();
    int tc = tid & 15, dbase = tid >> 4;
#pragma unroll
    for (int pass = 0; pass < 8; pass++) {
      int d = dbase + pass * 16;
      int byte = (d * 256 + tc * 16) ^ ((d & 7) << 4);
      uint4 v = *(const uint4*)(lds + byte);
      *(uint4*)(Vout + ((size_t)(bk * 128 + d)) * 2048 + t0g + tc * 8) = v;
    }
  }
}

// ---------------- causal GQA flash attention (r9 body + XCD-grouped 1D grid) ----------------
// 512 blocks: fid&7 -> (b,kvh) so each XCD's L2 holds one KV slice (1MB) + Q slice (2MB);
// 64 blocks/XCD = 2/CU exactly. Block handles q-tiles {pairId, 31-pairId} (uniform 33 iters).
// K/V double-buffered via global_load_lds w/ pre-swizzled source. exp2-domain softmax,
// defer-max THR=11.5, ones-MFMA row-sum, setprio. __launch_bounds__(256,4) caps VGPR 128
// (VGPR>128 halves occupancy -- r6/r8 lesson).
__global__ __launch_bounds__(256, 4) void k_attn(
    const u16* __restrict__ Q, const u16* __restrict__ Kb,
    const u16* __restrict__ Vt, u16* __restrict__ Y) {
  __shared__ char lds[73728];  // K0 16K | V0 16K | K1 16K | V1 16K | P 8K
  char* Ps = lds + 65536;
  int tid = threadIdx.x, w = tid >> 6, l = tid & 63, lg = l >> 4, ll = l & 15;
  int fid = blockIdx.x;
  int g = fid & 7, rank = fid >> 3;
  int b = g >> 2, kvh = g & 3;
  int h = kvh * 4 + (rank & 3);
  int pairId = rank >> 2;  // 0..15
  const u16* Kbase = Kb + ((size_t)b * 2048) * 512 + kvh * 128;
  const u16* Vbase = Vt + ((size_t)(b * 4 + kvh) * 128) * 2048;

  const bf16x8 vones = {(short)0x3F80, (short)0x3F80, (short)0x3F80, (short)0x3F80,
                        (short)0x3F80, (short)0x3F80, (short)0x3F80, (short)0x3F80};

#pragma unroll 1
  for (int qi = 0; qi < 2; qi++) {
    int qb = qi ? (31 - pairId) : pairId;
    int q0 = qb * 64;
    bf16x8 qf[4];
    {
      int qrow = b * 2048 + q0 + 16 * w + ll;
      const u16* qp = Q + (size_t)qrow * 2048 + h * 128;
#pragma unroll
      for (int ks = 0; ks < 4; ks++) qf[ks] = *(const bf16x8*)(qp + ks * 32 + lg * 8);
    }
    f32x4 o[8] = {};
    f32x4 lacc = {};
    float mrow[4];
#pragma unroll
    for (int r = 0; r < 4; r++) mrow[r] = -1e30f;

    auto stage = [&](int bi, int k0) {
      char* Kd = lds + (bi ? 32768 : 0);
      char* Vd = lds + (bi ? 49152 : 16384);
#pragma unroll
      for (int i = 0; i < 4; i++) {
        int c = i * 256 + tid;
        int dst = (i * 256 + (w << 6)) * 16;  // wave-uniform chunk base * 16B
        int krow = c >> 4, ksrc = (c & 15) ^ (krow & 7);
        gll16(Kbase + (size_t)(k0 + krow) * 512 + ksrc * 8, Kd + dst);
        int vd = c >> 3, vsrc = (c & 7) ^ (vd & 7);
        gll16(Vbase + (size_t)vd * 2048 + k0 + vsrc * 8, Vd + dst);
      }
    };

    stage(0, 0);
    asm volatile("s_waitcnt vmcnt(0)" ::: "memory");
    __syncthreads();

    int cur = 0;
    for (int it = 0; it <= qb; ++it) {
      if (it < qb) stage(cur ^ 1, (it + 1) * 64);  // async prefetch next tile
      char* Ks = lds + (cur ? 32768 : 0);
      char* Vs = lds + (cur ? 49152 : 16384);
      // S = Q K^T (per wave: 16 q-rows x 64 kv); log2e/sqrt(D) pre-folded into Q
      f32x4 s[4] = {};
      __builtin_amdgcn_s_setprio(1);
#pragma unroll
      for (int ks = 0; ks < 4; ks++) {
#pragma unroll
        for (int n = 0; n < 4; n++) {
          int row = 16 * n + ll;
          bf16x8 kf = *(const bf16x8*)(Ks + ((row * 256 + (lg + 4 * ks) * 16) ^ ((row & 7) << 4)));
          s[n] = __builtin_amdgcn_mfma_f32_16x16x32_bf16(qf[ks], kf, s[n], 0, 0, 0);
        }
      }
      __builtin_amdgcn_s_setprio(0);
      if (it == qb) {  // diagonal tile: causal mask
        int k0 = it * 64;
#pragma unroll
        for (int n = 0; n < 4; n++) {
          int kk = k0 + 16 * n + ll;
#pragma unroll
          for (int r = 0; r < 4; r++) {
            int qq = q0 + 16 * w + 4 * lg + r;
            if (kk > qq) s[n][r] = -1e30f;
          }
        }
      }
      // online softmax, exp2 domain (C layout: row = 4*lg + r, col = ll)
      float pmax[4];
#pragma unroll
      for (int r = 0; r < 4; r++) {
        float mx = fmaxf(fmaxf(s[0][r], s[1][r]), fmaxf(s[2][r], s[3][r]));
#pragma unroll
        for (int m = 1; m < 16; m <<= 1) mx = fmaxf(mx, __shfl_xor(mx, m));
        pmax[r] = mx;
      }
      float dmax = fmaxf(fmaxf(pmax[0] - mrow[0], pmax[1] - mrow[1]),
                         fmaxf(pmax[2] - mrow[2], pmax[3] - mrow[3]));
      if (__any(dmax > 11.5f)) {  // defer-max (log2 units; P bounded by 2^11.5)
#pragma unroll
        for (int r = 0; r < 4; r++) {
          float mn = fmaxf(mrow[r], pmax[r]);
          float al = exp2f(mrow[r] - mn);
          mrow[r] = mn;
          lacc[r] *= al;
#pragma unroll
          for (int n = 0; n < 8; n++) o[n][r] *= al;
        }
      }
      // exp2 + P (bf16) -> per-wave swizzled LDS tile (wave-local ds order)
#pragma unroll
      for (int r = 0; r < 4; r++) {
        int prow = 4 * lg + r;
#pragma unroll
        for (int n = 0; n < 4; n++) {
          float e = exp2f(s[n][r] - mrow[r]);
          int byte = (w << 11) + ((prow * 128 + (16 * n + ll) * 2) ^ ((prow & 7) << 4));
          *(u16*)(Ps + byte) = f2bf_fast(e);
        }
      }
      // O += P V ; l += P 1 (row-sum on the MFMA pipe)
      __builtin_amdgcn_s_setprio(1);
#pragma unroll
      for (int ks = 0; ks < 2; ks++) {
        bf16x8 pf = *(const bf16x8*)(Ps + (w << 11) + ((ll * 128 + (lg + 4 * ks) * 16) ^ ((ll & 7) << 4)));
        lacc = __builtin_amdgcn_mfma_f32_16x16x32_bf16(pf, vones, lacc, 0, 0, 0);
#pragma unroll
        for (int n = 0; n < 8; n++) {
          int row = 16 * n + ll;
          bf16x8 vf = *(const bf16x8*)(Vs + ((row * 128 + (lg + 4 * ks) * 16) ^ ((row & 7) << 4)));
          o[n] = __builtin_amdgcn_mfma_f32_16x16x32_bf16(pf, vf, o[n], 0, 0, 0);
        }
      }
      __builtin_amdgcn_s_setprio(0);
      // drain this iteration's prefetch, publish to all waves
      asm volatile("s_waitcnt vmcnt(0)" ::: "memory");
      __syncthreads();
      cur ^= 1;
    }
    // output
    float rl[4];
#pragma unroll
    for (int r = 0; r < 4; r++) rl[r] = 1.0f / lacc[r];
#pragma unroll
    for (int n = 0; n < 8; n++) {
      int col = h * 128 + 16 * n + ll;
#pragma unroll
      for (int r = 0; r < 4; r++) {
        int trow = b * 2048 + q0 + 16 * w + 4 * lg + r;
        Y[(size_t)trow * 2048 + col] = f2bf_fast(o[n][r] * rl[r]);
      }
    }
  }
}

extern "C" void kernel_launch(void* const* d_in, const int* in_sizes, int n_in,
                              void* d_out, int out_size, void* d_ws, size_t ws_size,
                              hipStream_t stream) {
  const float* x   = (const float*)d_in[0];
  const float* fc  = (const float*)d_in[1];
  const float* fs  = (const float*)d_in[2];
  const float* wq  = (const float*)d_in[3];
  const float* wk  = (const float*)d_in[4];
  const float* wv  = (const float*)d_in[5];
  const float* wo  = (const float*)d_in[6];
  const float* qnw = (const float*)d_in[7];
  const float* knw = (const float*)d_in[8];
  float* out = (float*)d_out;

  const size_t MB = 1ull << 20;
  char* ws = (char*)d_ws;
  u16* xb   = (u16*)(ws);             // 16 MB  x bf16
  u16* wqt  = (u16*)(ws + 16 * MB);   //  8 MB  wq^T bf16 [2048][2048]
  u16* wkvt = (u16*)(ws + 24 * MB);   //  4 MB  [wk^T;wv^T] bf16 [1024][2048]
  u16* wot  = (u16*)(ws + 28 * MB);   //  8 MB  wo^T bf16
  u16* Qb   = (u16*)(ws + 36 * MB);   // 16 MB  Q' bf16 (rms+rope, x log2e/sqrt(D))
  u16* Kbq  = (u16*)(ws + 52 * MB);   //  4 MB  K' bf16 (rms+rope)
  u16* Vtg  = (u16*)(ws + 56 * MB);   //  4 MB  V^T bf16 (b,kvh,d,t)
  u16* Yb   = (u16*)(ws + 60 * MB);   // 16 MB  attn out bf16

  hipLaunchKernelGGL(k_prep, dim3(6656), dim3(256), 0, stream,
                     x, xb, wq, wqt, wk, wv, wkvt, wo, wot);
  // fused QKV projection: Q (rms+rope+log2e-scale), K (rms+rope), V (transpose)
  hipLaunchKernelGGL((k_gemm<3>), dim3(24, 32), dim3(256), 0, stream,
                     xb, wqt, wkvt, (void*)Qb, Kbq, Vtg, 2048,
                     qnw, knw, fc, fs);
  hipLaunchKernelGGL(k_attn, dim3(512), dim3(256), 0, stream, Qb, Kbq, Vtg, Yb);
  hipLaunchKernelGGL((k_gemm<0>), dim3(16, 32), dim3(256), 0, stream,
                     Yb, wot, (const u16*)nullptr, (void*)out, (u16*)nullptr, (u16*)nullptr, 2048,
                     nullptr, nullptr, nullptr, nullptr);
}

// Round 11
// 234.826 us; speedup vs baseline: 1.0753x; 1.0753x over previous
//
#include <hip/hip_runtime.h>
#include <hip/hip_bf16.h>

using u16 = unsigned short;
using u32 = unsigned int;

typedef short bf16x8 __attribute__((ext_vector_type(8)));
typedef float f32x4 __attribute__((ext_vector_type(4)));

#define AS1 __attribute__((address_space(1)))
#define AS3 __attribute__((address_space(3)))

__device__ __forceinline__ void gll16(const void* g, void* l) {
  __builtin_amdgcn_global_load_lds((const AS1 u32*)g, (AS3 u32*)l, 16, 0, 0);
}

__device__ __forceinline__ u16 f2bf(float x) {  // round-to-nearest-even bf16
  u32 u = __builtin_bit_cast(u32, x);
  u32 r = (u + 0x7fffu + ((u >> 16) & 1u)) >> 16;
  return (u16)r;
}
__device__ __forceinline__ u32 pk2(float lo, float hi) {
  return (u32)f2bf(lo) | ((u32)f2bf(hi) << 16);
}
__device__ __forceinline__ u16 f2bf_fast(float x) {  // hw cvt (validated r5/r6)
  __hip_bfloat16 h = __float2bfloat16(x);
  return __builtin_bit_cast(u16, h);
}

// ---------------- merged prep: x cast (blocks 0..4095) + 4 weight transposes ----------------
__device__ __forceinline__ void trans64(const float* __restrict__ in, u16* __restrict__ out,
                                        int R, int Cc, int bx, int by, float (*tl)[65]) {
  int c0 = bx * 64, r0 = by * 64, tid = threadIdx.x;
#pragma unroll
  for (int i = 0; i < 16; i++) {
    int idx = i * 256 + tid; int tr = idx >> 6, tc = idx & 63;
    tl[tr][tc] = in[(size_t)(r0 + tr) * Cc + c0 + tc];
  }
  __syncthreads();
#pragma unroll
  for (int i = 0; i < 16; i++) {
    int idx = i * 256 + tid; int tr = idx >> 6, tc = idx & 63;
    out[(size_t)(c0 + tr) * R + r0 + tc] = f2bf(tl[tc][tr]);
  }
}

__global__ void k_prep(const float* __restrict__ x, u16* __restrict__ xb,
                       const float* __restrict__ wq, u16* __restrict__ wqt,
                       const float* __restrict__ wk, const float* __restrict__ wv,
                       u16* __restrict__ wkvt,
                       const float* __restrict__ wo, u16* __restrict__ wot) {
  __shared__ float tl[64][65];
  int gid = blockIdx.x;
  if (gid < 4096) {
    int i = gid * 256 + threadIdx.x;
    const float4* p = (const float4*)(x + (size_t)i * 8);
    float4 a = p[0], b = p[1];
    uint4 o;
    o.x = pk2(a.x, a.y); o.y = pk2(a.z, a.w);
    o.z = pk2(b.x, b.y); o.w = pk2(b.z, b.w);
    *(uint4*)(xb + (size_t)i * 8) = o;
  } else if (gid < 5120) {
    int t = gid - 4096; trans64(wq, wqt, 2048, 2048, t & 31, t >> 5, tl);
  } else if (gid < 5376) {
    int t = gid - 5120; trans64(wk, wkvt, 2048, 512, t & 7, t >> 3, tl);
  } else if (gid < 5632) {
    int t = gid - 5376; trans64(wv, wkvt + 512 * 2048, 2048, 512, t & 7, t >> 3, tl);
  } else {
    int t = gid - 5632; trans64(wo, wot, 2048, 2048, t & 31, t >> 5, tl);
  }
}

// ---------------- GEMM: C = A[M][K] x BT[N][K], 128x128 tile, BK=64, 4 waves ----------------
// MODE 0: C f32 [4096][2048] (O projection). grid (16,32).
// MODE 3: fused QKV. grid (24,32): bx<16 -> Q: rms+rope*(log2e/sqrt(D)) -> bf16 Cout;
//         bx 16..19 -> K: rms+rope -> Kout; bx 20..23 -> V: bf16^T -> Vout (b,kvh,d,t).
// Both grids XCD-swizzled (nwg % 8 == 0, bijective).
template <int MODE>
__global__ __launch_bounds__(256) void k_gemm(
    const u16* __restrict__ A, const u16* __restrict__ BT0, const u16* __restrict__ BT1,
    void* __restrict__ Cout, u16* __restrict__ Kout, u16* __restrict__ Vout, int K,
    const float* __restrict__ nwq, const float* __restrict__ nwk,
    const float* __restrict__ fc, const float* __restrict__ fs) {
  constexpr int NX = (MODE == 0) ? 16 : 24;
  constexpr int NWG = NX * 32;
  __shared__ char lds[32768];
  char* As = lds; char* Bs = lds + 16384;
  int tid = threadIdx.x, w = tid >> 6, l = tid & 63, lg = l >> 4, ll = l & 15;
  // XCD-aware bijective remap
  int lid = blockIdx.y * NX + blockIdx.x;
  int nid = (lid & 7) * (NWG >> 3) + (lid >> 3);
  int bxt = nid % NX;
  int bm0 = (nid / NX) * 128;
  bool qpath = (MODE == 0) || (bxt < 16);
  const u16* BT = qpath ? BT0 : BT1;
  int bn0 = qpath ? bxt * 128 : (bxt - 16) * 128;
  int wr = w >> 1, wc = w & 1;
  f32x4 acc[4][4] = {};
  for (int k0 = 0; k0 < K; k0 += 64) {
#pragma unroll
    for (int i = 0; i < 4; i++) {
      int base = i * 256 + (w << 6);       // wave-uniform chunk base
      int p = base + l;                    // this lane's 16B chunk
      int r = p >> 3, kc = (p & 7) ^ (r & 7);  // pre-swizzled global source
      gll16(A + (size_t)(bm0 + r) * K + k0 + kc * 8, As + base * 16);
      gll16(BT + (size_t)(bn0 + r) * K + k0 + kc * 8, Bs + base * 16);
    }
    asm volatile("s_waitcnt vmcnt(0)" ::: "memory");
    __syncthreads();
#pragma unroll
    for (int ks = 0; ks < 2; ks++) {
      bf16x8 af[4], bfr[4];
#pragma unroll
      for (int m = 0; m < 4; m++) {
        int row = 64 * wr + 16 * m + ll;
        af[m] = *(const bf16x8*)(As + row * 128 + (((lg + 4 * ks) ^ (row & 7)) << 4));
      }
#pragma unroll
      for (int n = 0; n < 4; n++) {
        int row = 64 * wc + 16 * n + ll;
        bfr[n] = *(const bf16x8*)(Bs + row * 128 + (((lg + 4 * ks) ^ (row & 7)) << 4));
      }
#pragma unroll
      for (int m = 0; m < 4; m++)
#pragma unroll
        for (int n = 0; n < 4; n++)
          acc[m][n] = __builtin_amdgcn_mfma_f32_16x16x32_bf16(af[m], bfr[n], acc[m][n], 0, 0, 0);
    }
    __syncthreads();
  }

  if (MODE == 0) {
    float* C = (float*)Cout;
#pragma unroll
    for (int m = 0; m < 4; m++)
#pragma unroll
      for (int n = 0; n < 4; n++) {
        int row = bm0 + 64 * wr + 16 * m + 4 * lg;
        int col = bn0 + 64 * wc + 16 * n + ll;
        float* cp = C + (size_t)row * 2048 + col;
#pragma unroll
        for (int r = 0; r < 4; r++) cp[(size_t)r * 2048] = acc[m][n][r];
      }
    return;
  }

  if (qpath || bn0 < 512) {
    // --- fused RMSNorm + RoPE + bf16 store (Q or K heads); all-lane straight-line
    // epilogue (r9-proven; half-lane predicated version regressed 24us -- r10 lesson) ---
    const float* nw = qpath ? nwq : nwk;
    u16* O = qpath ? (u16*)Cout : Kout;
    int ostride = qpath ? 2048 : 512;
    // Q: log2e/sqrt(128) (exp2-domain attention); K: 1
    float outscale = qpath ? 0.12751744843f : 1.0f;
    float* ssum = (float*)lds;  // [wr][64 rows][wc]
    float ps[4][4];
#pragma unroll
    for (int m = 0; m < 4; m++)
#pragma unroll
      for (int r = 0; r < 4; r++) {
        float p = 0.f;
#pragma unroll
        for (int n = 0; n < 4; n++) p += acc[m][n][r] * acc[m][n][r];
#pragma unroll
        for (int msk = 1; msk < 16; msk <<= 1) p += __shfl_xor(p, msk);
        ps[m][r] = p;
      }
    if (ll == 0) {
#pragma unroll
      for (int m = 0; m < 4; m++)
#pragma unroll
        for (int r = 0; r < 4; r++)
          ssum[wr * 128 + (16 * m + 4 * lg + r) * 2 + wc] = ps[m][r];
    }
    __syncthreads();
    float rs[4][4];
#pragma unroll
    for (int m = 0; m < 4; m++)
#pragma unroll
      for (int r = 0; r < 4; r++) {
        int rowl = 16 * m + 4 * lg + r;
        float tot = ssum[wr * 128 + rowl * 2] + ssum[wr * 128 + rowl * 2 + 1];
        rs[m][r] = rsqrtf(tot * (1.0f / 128.0f) + 1e-5f) * outscale;
      }
#pragma unroll
    for (int m = 0; m < 4; m++)
#pragma unroll
      for (int n = 0; n < 4; n++) {
        int d = 64 * wc + 16 * n + ll;     // dim within head (0..127)
        float wgt = nw[d];
        int i = d >> 1;
#pragma unroll
        for (int r = 0; r < 4; r++) {
          int row = bm0 + 64 * wr + 16 * m + 4 * lg + r;
          int t = row & 2047;
          float y = acc[m][n][r] * rs[m][r] * wgt;
          float p = __shfl_xor(y, 1);
          float c = fc[t * 64 + i], s = fs[t * 64 + i];
          float o = (ll & 1) ? (p * s + y * c) : (y * c - p * s);
          O[(size_t)row * ostride + bn0 + d] = f2bf(o);
        }
      }
  } else {
    // --- V: bf16 + transpose to (b,kvh,d,t) via swizzled LDS ---
    int b = bm0 >> 11, t0g = bm0 & 2047;
    int kvh = (bn0 - 512) >> 7;
    int bk = b * 4 + kvh;
#pragma unroll
    for (int m = 0; m < 4; m++)
#pragma unroll
      for (int n = 0; n < 4; n++) {
        int d = 64 * wc + 16 * n + ll;
        int tloc = 64 * wr + 16 * m + 4 * lg;
        u32 w0 = pk2(acc[m][n][0], acc[m][n][1]);
        u32 w1 = pk2(acc[m][n][2], acc[m][n][3]);
        int byte = (d * 256 + tloc * 2) ^ ((d & 7) << 4);
        *(uint2*)(lds + byte) = make_uint2(w0, w1);
      }
    __syncthreads();
    int tc = tid & 15, dbase = tid >> 4;
#pragma unroll
    for (int pass = 0; pass < 8; pass++) {
      int d = dbase + pass * 16;
      int byte = (d * 256 + tc * 16) ^ ((d & 7) << 4);
      uint4 v = *(const uint4*)(lds + byte);
      *(uint4*)(Vout + ((size_t)(bk * 128 + d)) * 2048 + t0g + tc * 8) = v;
    }
  }
}

// ---------------- causal GQA flash attention (XCD-grouped 1D grid) ----------------
// 512 blocks: fid&7 -> (b,kvh) so each XCD's L2 holds one KV slice (1MB) + Q slice (2MB);
// 64 blocks/XCD = 2/CU exactly. Block handles q-tiles {pairId, 31-pairId} (uniform 33 iters).
// K/V double-buffered via global_load_lds w/ pre-swizzled source. exp2-domain softmax,
// defer-max THR=11.5, ones-MFMA row-sum, setprio. __launch_bounds__(256,4) caps VGPR 128
// (VGPR>128 halves occupancy -- r6/r8 lesson).
__global__ __launch_bounds__(256, 4) void k_attn(
    const u16* __restrict__ Q, const u16* __restrict__ Kb,
    const u16* __restrict__ Vt, u16* __restrict__ Y) {
  __shared__ char lds[73728];  // K0 16K | V0 16K | K1 16K | V1 16K | P 8K
  char* Ps = lds + 65536;
  int tid = threadIdx.x, w = tid >> 6, l = tid & 63, lg = l >> 4, ll = l & 15;
  int fid = blockIdx.x;
  int g = fid & 7, rank = fid >> 3;
  int b = g >> 2, kvh = g & 3;
  int h = kvh * 4 + (rank & 3);
  int pairId = rank >> 2;  // 0..15
  const u16* Kbase = Kb + ((size_t)b * 2048) * 512 + kvh * 128;
  const u16* Vbase = Vt + ((size_t)(b * 4 + kvh) * 128) * 2048;

  const bf16x8 vones = {(short)0x3F80, (short)0x3F80, (short)0x3F80, (short)0x3F80,
                        (short)0x3F80, (short)0x3F80, (short)0x3F80, (short)0x3F80};

#pragma unroll 1
  for (int qi = 0; qi < 2; qi++) {
    int qb = qi ? (31 - pairId) : pairId;
    int q0 = qb * 64;
    bf16x8 qf[4];
    {
      int qrow = b * 2048 + q0 + 16 * w + ll;
      const u16* qp = Q + (size_t)qrow * 2048 + h * 128;
#pragma unroll
      for (int ks = 0; ks < 4; ks++) qf[ks] = *(const bf16x8*)(qp + ks * 32 + lg * 8);
    }
    f32x4 o[8] = {};
    f32x4 lacc = {};
    float mrow[4];
#pragma unroll
    for (int r = 0; r < 4; r++) mrow[r] = -1e30f;

    auto stage = [&](int bi, int k0) {
      char* Kd = lds + (bi ? 32768 : 0);
      char* Vd = lds + (bi ? 49152 : 16384);
#pragma unroll
      for (int i = 0; i < 4; i++) {
        int c = i * 256 + tid;
        int dst = (i * 256 + (w << 6)) * 16;  // wave-uniform chunk base * 16B
        int krow = c >> 4, ksrc = (c & 15) ^ (krow & 7);
        gll16(Kbase + (size_t)(k0 + krow) * 512 + ksrc * 8, Kd + dst);
        int vd = c >> 3, vsrc = (c & 7) ^ (vd & 7);
        gll16(Vbase + (size_t)vd * 2048 + k0 + vsrc * 8, Vd + dst);
      }
    };

    stage(0, 0);
    asm volatile("s_waitcnt vmcnt(0)" ::: "memory");
    __syncthreads();

    int cur = 0;
    for (int it = 0; it <= qb; ++it) {
      if (it < qb) stage(cur ^ 1, (it + 1) * 64);  // async prefetch next tile
      char* Ks = lds + (cur ? 32768 : 0);
      char* Vs = lds + (cur ? 49152 : 16384);
      // S = Q K^T (per wave: 16 q-rows x 64 kv); log2e/sqrt(D) pre-folded into Q
      f32x4 s[4] = {};
      __builtin_amdgcn_s_setprio(1);
#pragma unroll
      for (int ks = 0; ks < 4; ks++) {
#pragma unroll
        for (int n = 0; n < 4; n++) {
          int row = 16 * n + ll;
          bf16x8 kf = *(const bf16x8*)(Ks + ((row * 256 + (lg + 4 * ks) * 16) ^ ((row & 7) << 4)));
          s[n] = __builtin_amdgcn_mfma_f32_16x16x32_bf16(qf[ks], kf, s[n], 0, 0, 0);
        }
      }
      __builtin_amdgcn_s_setprio(0);
      if (it == qb) {  // diagonal tile: causal mask
        int k0 = it * 64;
#pragma unroll
        for (int n = 0; n < 4; n++) {
          int kk = k0 + 16 * n + ll;
#pragma unroll
          for (int r = 0; r < 4; r++) {
            int qq = q0 + 16 * w + 4 * lg + r;
            if (kk > qq) s[n][r] = -1e30f;
          }
        }
      }
      // online softmax, exp2 domain (C layout: row = 4*lg + r, col = ll)
      float pmax[4];
#pragma unroll
      for (int r = 0; r < 4; r++) {
        float mx = fmaxf(fmaxf(s[0][r], s[1][r]), fmaxf(s[2][r], s[3][r]));
#pragma unroll
        for (int m = 1; m < 16; m <<= 1) mx = fmaxf(mx, __shfl_xor(mx, m));
        pmax[r] = mx;
      }
      float dmax = fmaxf(fmaxf(pmax[0] - mrow[0], pmax[1] - mrow[1]),
                         fmaxf(pmax[2] - mrow[2], pmax[3] - mrow[3]));
      if (__any(dmax > 11.5f)) {  // defer-max (log2 units; P bounded by 2^11.5)
#pragma unroll
        for (int r = 0; r < 4; r++) {
          float mn = fmaxf(mrow[r], pmax[r]);
          float al = exp2f(mrow[r] - mn);
          mrow[r] = mn;
          lacc[r] *= al;
#pragma unroll
          for (int n = 0; n < 8; n++) o[n][r] *= al;
        }
      }
      // exp2 + P (bf16) -> per-wave swizzled LDS tile (wave-local ds order)
#pragma unroll
      for (int r = 0; r < 4; r++) {
        int prow = 4 * lg + r;
#pragma unroll
        for (int n = 0; n < 4; n++) {
          float e = exp2f(s[n][r] - mrow[r]);
          int byte = (w << 11) + ((prow * 128 + (16 * n + ll) * 2) ^ ((prow & 7) << 4));
          *(u16*)(Ps + byte) = f2bf_fast(e);
        }
      }
      // O += P V ; l += P 1 (row-sum on the MFMA pipe)
      __builtin_amdgcn_s_setprio(1);
#pragma unroll
      for (int ks = 0; ks < 2; ks++) {
        bf16x8 pf = *(const bf16x8*)(Ps + (w << 11) + ((ll * 128 + (lg + 4 * ks) * 16) ^ ((ll & 7) << 4)));
        lacc = __builtin_amdgcn_mfma_f32_16x16x32_bf16(pf, vones, lacc, 0, 0, 0);
#pragma unroll
        for (int n = 0; n < 8; n++) {
          int row = 16 * n + ll;
          bf16x8 vf = *(const bf16x8*)(Vs + ((row * 128 + (lg + 4 * ks) * 16) ^ ((row & 7) << 4)));
          o[n] = __builtin_amdgcn_mfma_f32_16x16x32_bf16(pf, vf, o[n], 0, 0, 0);
        }
      }
      __builtin_amdgcn_s_setprio(0);
      // drain this iteration's prefetch, publish to all waves
      asm volatile("s_waitcnt vmcnt(0)" ::: "memory");
      __syncthreads();
      cur ^= 1;
    }
    // output
    float rl[4];
#pragma unroll
    for (int r = 0; r < 4; r++) rl[r] = 1.0f / lacc[r];
#pragma unroll
    for (int n = 0; n < 8; n++) {
      int col = h * 128 + 16 * n + ll;
#pragma unroll
      for (int r = 0; r < 4; r++) {
        int trow = b * 2048 + q0 + 16 * w + 4 * lg + r;
        Y[(size_t)trow * 2048 + col] = f2bf_fast(o[n][r] * rl[r]);
      }
    }
  }
}

extern "C" void kernel_launch(void* const* d_in, const int* in_sizes, int n_in,
                              void* d_out, int out_size, void* d_ws, size_t ws_size,
                              hipStream_t stream) {
  const float* x   = (const float*)d_in[0];
  const float* fc  = (const float*)d_in[1];
  const float* fs  = (const float*)d_in[2];
  const float* wq  = (const float*)d_in[3];
  const float* wk  = (const float*)d_in[4];
  const float* wv  = (const float*)d_in[5];
  const float* wo  = (const float*)d_in[6];
  const float* qnw = (const float*)d_in[7];
  const float* knw = (const float*)d_in[8];
  float* out = (float*)d_out;

  const size_t MB = 1ull << 20;
  char* ws = (char*)d_ws;
  u16* xb   = (u16*)(ws);             // 16 MB  x bf16
  u16* wqt  = (u16*)(ws + 16 * MB);   //  8 MB  wq^T bf16 [2048][2048]
  u16* wkvt = (u16*)(ws + 24 * MB);   //  4 MB  [wk^T;wv^T] bf16 [1024][2048]
  u16* wot  = (u16*)(ws + 28 * MB);   //  8 MB  wo^T bf16
  u16* Qb   = (u16*)(ws + 36 * MB);   // 16 MB  Q' bf16 (rms+rope, x log2e/sqrt(D))
  u16* Kbq  = (u16*)(ws + 52 * MB);   //  4 MB  K' bf16 (rms+rope)
  u16* Vtg  = (u16*)(ws + 56 * MB);   //  4 MB  V^T bf16 (b,kvh,d,t)
  u16* Yb   = (u16*)(ws + 60 * MB);   // 16 MB  attn out bf16

  hipLaunchKernelGGL(k_prep, dim3(6656), dim3(256), 0, stream,
                     x, xb, wq, wqt, wk, wv, wkvt, wo, wot);
  // fused QKV projection: Q (rms+rope+log2e-scale), K (rms+rope), V (transpose)
  hipLaunchKernelGGL((k_gemm<3>), dim3(24, 32), dim3(256), 0, stream,
                     xb, wqt, wkvt, (void*)Qb, Kbq, Vtg, 2048,
                     qnw, knw, fc, fs);
  hipLaunchKernelGGL(k_attn, dim3(512), dim3(256), 0, stream, Qb, Kbq, Vtg, Yb);
  hipLaunchKernelGGL((k_gemm<0>), dim3(16, 32), dim3(256), 0, stream,
                     Yb, wot, (const u16*)nullptr, (void*)out, (u16*)nullptr, (u16*)nullptr, 2048,
                     nullptr, nullptr, nullptr, nullptr);
}